// Round 1
// baseline (25.013 us; speedup 1.0000x reference)
//
#include <hip/hip_runtime.h>
#include <math.h>

#define DEGREE 20
#define NW (DEGREE + 1)

// ---------- complex helpers ----------
__device__ __forceinline__ float2 cmul(float2 a, float2 b) {
    return make_float2(a.x * b.x - a.y * b.y, a.x * b.y + a.y * b.x);
}
__device__ __forceinline__ float2 cfma(float2 a, float2 b, float2 acc) {
    // acc + a*b
    acc.x = fmaf(a.x, b.x, fmaf(-a.y, b.y, acc.x));
    acc.y = fmaf(a.x, b.y, fmaf(a.y, b.x, acc.y));
    return acc;
}

// A = RZ(t2) @ RY(t1) @ RX(t0), 2x2 complex
__device__ void build_su2(float t0, float t1, float t2, float2 A[2][2]) {
    float c0 = cosf(0.5f * t0), s0 = sinf(0.5f * t0);
    float c1 = cosf(0.5f * t1), s1 = sinf(0.5f * t1);
    float c2 = cosf(0.5f * t2), s2 = sinf(0.5f * t2);
    float2 RX[2][2] = {{{c0, 0.f}, {0.f, -s0}}, {{0.f, -s0}, {c0, 0.f}}};
    float2 RY[2][2] = {{{c1, 0.f}, {-s1, 0.f}}, {{s1, 0.f}, {c1, 0.f}}};
    float2 RZ[2][2] = {{{c2, -s2}, {0.f, 0.f}}, {{0.f, 0.f}, {c2, s2}}};
    float2 T[2][2];
    for (int i = 0; i < 2; ++i)
        for (int j = 0; j < 2; ++j) {
            float2 acc = {0.f, 0.f};
            for (int k = 0; k < 2; ++k) acc = cfma(RY[i][k], RX[k][j], acc);
            T[i][j] = acc;
        }
    for (int i = 0; i < 2; ++i)
        for (int j = 0; j < 2; ++j) {
            float2 acc = {0.f, 0.f};
            for (int k = 0; k < 2; ++k) acc = cfma(RZ[i][k], T[k][j], acc);
            A[i][j] = acc;
        }
}

// One tiny block: W[k] = CZ * kron(A_k, B_k) for k=0..20, plus theta/2 copy.
__global__ void build_w_kernel(const float* __restrict__ theta,
                               const float* __restrict__ phi,
                               float2* __restrict__ Wout,    // [21][4][4]
                               float* __restrict__ thh) {    // [20][2] = theta*0.5
    int k = threadIdx.x;
    if (k < DEGREE * 2) thh[k] = 0.5f * theta[k];
    if (k < NW) {
        const float* p = phi + 6 * k;
        float2 A[2][2], B[2][2];
        build_su2(p[0], p[1], p[2], A);
        build_su2(p[3], p[4], p[5], B);
        for (int i = 0; i < 2; ++i)
            for (int pp = 0; pp < 2; ++pp)
                for (int j = 0; j < 2; ++j)
                    for (int q = 0; q < 2; ++q) {
                        int r = 2 * i + pp, c = 2 * j + q;
                        float2 m = cmul(A[i][j], B[pp][q]);
                        if (r == 3) { m.x = -m.x; m.y = -m.y; }  // CZ row 3
                        Wout[k * 16 + r * 4 + c] = m;
                    }
    }
}

__global__ __launch_bounds__(256) void dqc1_kernel(
    const float* __restrict__ x, const float2* __restrict__ W,
    const float* __restrict__ thh, float* __restrict__ out, int n) {
    __shared__ float2 sW[NW * 16];
    __shared__ float sTh[DEGREE * 2];
    for (int i = threadIdx.x; i < NW * 16; i += blockDim.x) sW[i] = W[i];
    if (threadIdx.x < DEGREE * 2) sTh[threadIdx.x] = thh[threadIdx.x];
    __syncthreads();

    int gid = blockIdx.x * blockDim.x + threadIdx.x;
    if (gid >= n) return;
    float xv = x[gid];

    // v = W0 * e0 = column 0 of W0
    float2 v0 = sW[0], v1 = sW[4], v2 = sW[8], v3 = sW[12];

#pragma unroll
    for (int k = 0; k < DEGREE; ++k) {
        if (k > 0) {
            // v <- W_k v  (4x4 complex matvec, W broadcast from LDS)
            const float2* Wk = &sW[k * 16];
            float2 n0 = cmul(Wk[0], v0);
            n0 = cfma(Wk[1], v1, n0); n0 = cfma(Wk[2], v2, n0); n0 = cfma(Wk[3], v3, n0);
            float2 n1 = cmul(Wk[4], v0);
            n1 = cfma(Wk[5], v1, n1); n1 = cfma(Wk[6], v2, n1); n1 = cfma(Wk[7], v3, n1);
            float2 n2 = cmul(Wk[8], v0);
            n2 = cfma(Wk[9], v1, n2); n2 = cfma(Wk[10], v2, n2); n2 = cfma(Wk[11], v3, n2);
            float2 n3 = cmul(Wk[12], v0);
            n3 = cfma(Wk[13], v1, n3); n3 = cfma(Wk[14], v2, n3); n3 = cfma(Wk[15], v3, n3);
            v0 = n0; v1 = n1; v2 = n2; v3 = n3;
        }
        // S_k = RX(th0*x) (wire1, bit1) (x) RX(th1*x) (wire2, bit0)
        float sa, ca, sb, cb;
        __sincosf(sTh[2 * k] * xv, &sa, &ca);
        __sincosf(sTh[2 * k + 1] * xv, &sb, &cb);
        // b-stage on pairs (v0,v1),(v2,v3):  v0' = cb v0 - i sb v1 ; v1' = -i sb v0 + cb v1
        float2 u0, u1, u2, u3;
        u0.x = fmaf(cb, v0.x, sb * v1.y);  u0.y = fmaf(cb, v0.y, -sb * v1.x);
        u1.x = fmaf(cb, v1.x, sb * v0.y);  u1.y = fmaf(cb, v1.y, -sb * v0.x);
        u2.x = fmaf(cb, v2.x, sb * v3.y);  u2.y = fmaf(cb, v2.y, -sb * v3.x);
        u3.x = fmaf(cb, v3.x, sb * v2.y);  u3.y = fmaf(cb, v3.y, -sb * v2.x);
        // a-stage on pairs (u0,u2),(u1,u3)
        v0.x = fmaf(ca, u0.x, sa * u2.y);  v0.y = fmaf(ca, u0.y, -sa * u2.x);
        v2.x = fmaf(ca, u2.x, sa * u0.y);  v2.y = fmaf(ca, u2.y, -sa * u0.x);
        v1.x = fmaf(ca, u1.x, sa * u3.y);  v1.y = fmaf(ca, u1.y, -sa * u3.x);
        v3.x = fmaf(ca, u3.x, sa * u1.y);  v3.y = fmaf(ca, u3.y, -sa * u1.x);
    }

    // ans = Re( row0(W20) . v )
    const float2* Wf = &sW[DEGREE * 16];
    float ans = Wf[0].x * v0.x - Wf[0].y * v0.y;
    ans += Wf[1].x * v1.x - Wf[1].y * v1.y;
    ans += Wf[2].x * v2.x - Wf[2].y * v2.y;
    ans += Wf[3].x * v3.x - Wf[3].y * v3.y;
    out[gid] = ans;
}

extern "C" void kernel_launch(void* const* d_in, const int* in_sizes, int n_in,
                              void* d_out, int out_size, void* d_ws, size_t ws_size,
                              hipStream_t stream) {
    const float* x = (const float*)d_in[0];      // [N]
    const float* theta = (const float*)d_in[1];  // [20][2]
    const float* phi = (const float*)d_in[2];    // [21][6]
    float* out = (float*)d_out;
    int n = in_sizes[0];

    float2* Wbuf = (float2*)d_ws;                      // 21*16 float2 = 2688 B
    float* thh = (float*)((char*)d_ws + NW * 16 * sizeof(float2));  // 40 floats

    build_w_kernel<<<1, 64, 0, stream>>>(theta, phi, Wbuf, thh);
    int block = 256;
    int grid = (n + block - 1) / block;
    dqc1_kernel<<<grid, block, 0, stream>>>(x, Wbuf, thh, out, n);
}

// Round 2
// 21.447 us; speedup vs baseline: 1.1663x; 1.1663x over previous
//
#include <hip/hip_runtime.h>
#include <math.h>

#define DEGREE 20
#define NW (DEGREE + 1)
#define INV_4PI 0.07957747154594767f   // 1/(4*pi): angle t*x -> sin(t*x/2) arg in revolutions

// ---------- complex helpers ----------
__device__ __forceinline__ float2 cmul(float2 a, float2 b) {
    return make_float2(a.x * b.x - a.y * b.y, a.x * b.y + a.y * b.x);
}
__device__ __forceinline__ float2 cfma(float2 a, float2 b, float2 acc) {
    acc.x = fmaf(a.x, b.x, fmaf(-a.y, b.y, acc.x));
    acc.y = fmaf(a.x, b.y, fmaf(a.y, b.x, acc.y));
    return acc;
}

// A = RZ(t2) @ RY(t1) @ RX(t0), 2x2 complex (accurate trig; one-time per block)
__device__ void build_su2(float t0, float t1, float t2, float2 A[2][2]) {
    float c0 = cosf(0.5f * t0), s0 = sinf(0.5f * t0);
    float c1 = cosf(0.5f * t1), s1 = sinf(0.5f * t1);
    float c2 = cosf(0.5f * t2), s2 = sinf(0.5f * t2);
    float2 RX[2][2] = {{{c0, 0.f}, {0.f, -s0}}, {{0.f, -s0}, {c0, 0.f}}};
    float2 RY[2][2] = {{{c1, 0.f}, {-s1, 0.f}}, {{s1, 0.f}, {c1, 0.f}}};
    float2 RZ[2][2] = {{{c2, -s2}, {0.f, 0.f}}, {{0.f, 0.f}, {c2, s2}}};
    float2 T[2][2];
    for (int i = 0; i < 2; ++i)
        for (int j = 0; j < 2; ++j) {
            float2 acc = {0.f, 0.f};
            for (int k = 0; k < 2; ++k) acc = cfma(RY[i][k], RX[k][j], acc);
            T[i][j] = acc;
        }
    for (int i = 0; i < 2; ++i)
        for (int j = 0; j < 2; ++j) {
            float2 acc = {0.f, 0.f};
            for (int k = 0; k < 2; ++k) acc = cfma(RZ[i][k], T[k][j], acc);
            A[i][j] = acc;
        }
}

// hardware sin/cos: input in revolutions (v_sin_f32: D = sin(S0 * 2pi))
__device__ __forceinline__ float hw_sin(float rev) {
    float r;
    asm("v_sin_f32 %0, %1" : "=v"(r) : "v"(rev));
    return r;
}
__device__ __forceinline__ float hw_cos(float rev) {
    float r;
    asm("v_cos_f32 %0, %1" : "=v"(r) : "v"(rev));
    return r;
}

__global__ __launch_bounds__(256) void dqc1_fused(
    const float* __restrict__ x, const float* __restrict__ theta,
    const float* __restrict__ phi, float* __restrict__ out, int n) {
    __shared__ float2 sW[NW * 16];     // 21 x 4x4 complex
    __shared__ float sPre[DEGREE * 2]; // theta * 1/(4pi): arg in revolutions

    int t = threadIdx.x;
    if (t < DEGREE * 2) sPre[t] = theta[t] * INV_4PI;
    if (t < NW) {
        const float* p = phi + 6 * t;
        float2 A[2][2], B[2][2];
        build_su2(p[0], p[1], p[2], A);
        build_su2(p[3], p[4], p[5], B);
        for (int i = 0; i < 2; ++i)
            for (int pp = 0; pp < 2; ++pp)
                for (int j = 0; j < 2; ++j)
                    for (int q = 0; q < 2; ++q) {
                        int r = 2 * i + pp, c = 2 * j + q;
                        float2 m = cmul(A[i][j], B[pp][q]);
                        if (r == 3) { m.x = -m.x; m.y = -m.y; }  // CZ
                        sW[t * 16 + r * 4 + c] = m;
                    }
    }
    __syncthreads();

    int gid = blockIdx.x * blockDim.x + t;
    if (gid >= n) return;
    float xv = x[gid];

    // v = W0 * e0 = column 0 of W0
    float2 v0 = sW[0], v1 = sW[4], v2 = sW[8], v3 = sW[12];

#pragma unroll
    for (int k = 0; k < DEGREE; ++k) {
        if (k > 0) {
            // v <- W_k v (dense 4x4 complex matvec, wave-uniform LDS broadcast)
            const float2* Wk = &sW[k * 16];
            float2 n0 = cmul(Wk[0], v0);
            n0 = cfma(Wk[1], v1, n0); n0 = cfma(Wk[2], v2, n0); n0 = cfma(Wk[3], v3, n0);
            float2 n1 = cmul(Wk[4], v0);
            n1 = cfma(Wk[5], v1, n1); n1 = cfma(Wk[6], v2, n1); n1 = cfma(Wk[7], v3, n1);
            float2 n2 = cmul(Wk[8], v0);
            n2 = cfma(Wk[9], v1, n2); n2 = cfma(Wk[10], v2, n2); n2 = cfma(Wk[11], v3, n2);
            float2 n3 = cmul(Wk[12], v0);
            n3 = cfma(Wk[13], v1, n3); n3 = cfma(Wk[14], v2, n3); n3 = cfma(Wk[15], v3, n3);
            v0 = n0; v1 = n1; v2 = n2; v3 = n3;
        }
        // S_k = RX(th0*x) (wire1/bit1) (x) RX(th1*x) (wire2/bit0); args in revolutions
        float ra = sPre[2 * k] * xv;
        float rb = sPre[2 * k + 1] * xv;
        float sa = hw_sin(ra), ca = hw_cos(ra);
        float sb = hw_sin(rb), cb = hw_cos(rb);
        // b-stage on pairs (v0,v1),(v2,v3): v0' = cb v0 - i sb v1; v1' = -i sb v0 + cb v1
        float2 u0, u1, u2, u3;
        u0.x = fmaf(cb, v0.x, sb * v1.y);  u0.y = fmaf(cb, v0.y, -sb * v1.x);
        u1.x = fmaf(cb, v1.x, sb * v0.y);  u1.y = fmaf(cb, v1.y, -sb * v0.x);
        u2.x = fmaf(cb, v2.x, sb * v3.y);  u2.y = fmaf(cb, v2.y, -sb * v3.x);
        u3.x = fmaf(cb, v3.x, sb * v2.y);  u3.y = fmaf(cb, v3.y, -sb * v2.x);
        // a-stage on pairs (u0,u2),(u1,u3)
        v0.x = fmaf(ca, u0.x, sa * u2.y);  v0.y = fmaf(ca, u0.y, -sa * u2.x);
        v2.x = fmaf(ca, u2.x, sa * u0.y);  v2.y = fmaf(ca, u2.y, -sa * u0.x);
        v1.x = fmaf(ca, u1.x, sa * u3.y);  v1.y = fmaf(ca, u1.y, -sa * u3.x);
        v3.x = fmaf(ca, u3.x, sa * u1.y);  v3.y = fmaf(ca, u3.y, -sa * u1.x);
    }

    // ans = Re( row0(W20) . v )
    const float2* Wf = &sW[DEGREE * 16];
    float ans = Wf[0].x * v0.x - Wf[0].y * v0.y;
    ans += Wf[1].x * v1.x - Wf[1].y * v1.y;
    ans += Wf[2].x * v2.x - Wf[2].y * v2.y;
    ans += Wf[3].x * v3.x - Wf[3].y * v3.y;
    out[gid] = ans;
}

extern "C" void kernel_launch(void* const* d_in, const int* in_sizes, int n_in,
                              void* d_out, int out_size, void* d_ws, size_t ws_size,
                              hipStream_t stream) {
    const float* x = (const float*)d_in[0];      // [N]
    const float* theta = (const float*)d_in[1];  // [20][2]
    const float* phi = (const float*)d_in[2];    // [21][6]
    float* out = (float*)d_out;
    int n = in_sizes[0];

    int block = 256;
    int grid = (n + block - 1) / block;
    dqc1_fused<<<grid, block, 0, stream>>>(x, theta, phi, out, n);
}